// Round 7
// baseline (227.159 us; speedup 1.0000x reference)
//
#include <hip/hip_runtime.h>

typedef __bf16 bf16_t;
typedef bf16_t bf16x8 __attribute__((ext_vector_type(8)));
typedef unsigned short u16x8 __attribute__((ext_vector_type(8)));
typedef float f32x4 __attribute__((ext_vector_type(4)));
typedef unsigned int u32x4 __attribute__((ext_vector_type(4)));

union BF8 { u16x8 u; bf16x8 b; };

__device__ __forceinline__ unsigned short f2bf(float f) {
  unsigned int u = __float_as_uint(f);
  unsigned int r = (u + 0x7FFFu + ((u >> 16) & 1u)) >> 16;
  return (unsigned short)r;
}
__device__ __forceinline__ float bf2f(unsigned short s) {
  return __uint_as_float(((unsigned int)s) << 16);
}

// ---------------- prep: weights -> bf16 (W1/W2 hi+lo, W single bf16) ---------
__global__ __launch_bounds__(256) void kprep(const float* __restrict__ W1,
                                             const float* __restrict__ W2,
                                             const float* __restrict__ W,
                                             unsigned short* __restrict__ W1h,
                                             unsigned short* __restrict__ W1l,
                                             unsigned short* __restrict__ W2h,
                                             unsigned short* __restrict__ W2l,
                                             unsigned short* __restrict__ Wbh) {
  int idx = blockIdx.x * 256 + threadIdx.x;
  if (idx < 204800) {
    int c = idx / 800, k = idx - c * 800;
    int a = c >> 6, o = c & 63;
    float v = (k < 784) ? W1[(a * 784 + k) * 64 + o] : 0.f;
    unsigned short hi = f2bf(v);
    W1h[idx] = hi;
    W1l[idx] = f2bf(v - bf2f(hi));
  }
  if (idx < 16384) {
    int a = idx >> 12, o = (idx >> 6) & 63, k = idx & 63;
    float v = W2[(a * 64 + k) * 64 + o];
    unsigned short hi = f2bf(v);
    W2h[idx] = hi;
    W2l[idx] = f2bf(v - bf2f(hi));
  }
  if (idx < 81920) {
    Wbh[idx] = f2bf(W[idx]);
  }
}

// ---------------- kA: h = relu(x@W1 + b1), split-bf16, -> packed u32 ---------
// BM=64 (1 M-tile/wave), grid 512: 2 blocks/CU of work, 3 resident (LDS 52KB)
// so staging latency of one block overlaps MFMA of another. No nt hints.
__global__ __launch_bounds__(256, 3) void kA(const float* __restrict__ x,
                                             const float* __restrict__ b1,
                                             const unsigned short* __restrict__ W1h,
                                             const unsigned short* __restrict__ W1l,
                                             unsigned int* __restrict__ H) {
  __shared__ unsigned short xsh[64 * 40];
  __shared__ unsigned short xsl[64 * 40];
  __shared__ unsigned short wsh[256 * 40];
  __shared__ unsigned short wsl[256 * 40];
  __shared__ float b1s[256];
  const int tid = threadIdx.x;
  const int w   = tid >> 6;
  const int l   = tid & 63;
  const int l15 = l & 15;
  const int lg4 = l >> 4;
  const int k8  = lg4 * 8;
  const int b0  = blockIdx.x * 64;

  b1s[tid] = b1[tid];

  const f32x4 fz = {0.f, 0.f, 0.f, 0.f};
  f32x4 acc[16];
#pragma unroll
  for (int n = 0; n < 16; ++n) acc[n] = fz;

  const int srow = tid >> 2;       // x staging row 0..63
  const int scb  = (tid & 3) * 8;  // k-offset 0,8,16,24

  for (int ks = 0; ks < 25; ++ks) {
    const int k0 = ks * 32;
    __syncthreads();
    {  // stage x rows -> hi/lo bf16 planes (zero-pad K 784->800)
      unsigned int ph[4], pl[4];
      if (k0 + scb < 784) {
        const float4* px = (const float4*)(x + (size_t)(b0 + srow) * 784 + k0 + scb);
#pragma unroll
        for (int q = 0; q < 2; ++q) {
          float4 v = px[q];
          unsigned short hx = f2bf(v.x), hy = f2bf(v.y), hz = f2bf(v.z), hw = f2bf(v.w);
          unsigned short lx = f2bf(v.x - bf2f(hx)), ly = f2bf(v.y - bf2f(hy));
          unsigned short lz = f2bf(v.z - bf2f(hz)), lw = f2bf(v.w - bf2f(hw));
          ph[2 * q]     = (unsigned int)hx | ((unsigned int)hy << 16);
          ph[2 * q + 1] = (unsigned int)hz | ((unsigned int)hw << 16);
          pl[2 * q]     = (unsigned int)lx | ((unsigned int)ly << 16);
          pl[2 * q + 1] = (unsigned int)lz | ((unsigned int)lw << 16);
        }
      } else {
#pragma unroll
        for (int q = 0; q < 4; ++q) { ph[q] = 0u; pl[q] = 0u; }
      }
      uint4 a0 = {ph[0], ph[1], ph[2], ph[3]};
      uint4 c0 = {pl[0], pl[1], pl[2], pl[3]};
      *(uint4*)&xsh[srow * 40 + scb] = a0;
      *(uint4*)&xsl[srow * 40 + scb] = c0;
    }
    {  // stage W1 hi/lo: thread = output column
      const unsigned short* ph = W1h + (size_t)tid * 800 + k0;
      const unsigned short* pl = W1l + (size_t)tid * 800 + k0;
#pragma unroll
      for (int q = 0; q < 4; ++q) {
        *(uint4*)&wsh[tid * 40 + q * 8] = *(const uint4*)(ph + q * 8);
        *(uint4*)&wsl[tid * 40 + q * 8] = *(const uint4*)(pl + q * 8);
      }
    }
    __syncthreads();
    bf16x8 ah = *(const bf16x8*)&xsh[(w * 16 + l15) * 40 + k8];
    bf16x8 al = *(const bf16x8*)&xsl[(w * 16 + l15) * 40 + k8];
#pragma unroll
    for (int nt = 0; nt < 16; ++nt) {
      bf16x8 bh = *(const bf16x8*)&wsh[(nt * 16 + l15) * 40 + k8];
      bf16x8 bl = *(const bf16x8*)&wsl[(nt * 16 + l15) * 40 + k8];
      acc[nt] = __builtin_amdgcn_mfma_f32_16x16x32_bf16(ah, bh, acc[nt], 0, 0, 0);
      acc[nt] = __builtin_amdgcn_mfma_f32_16x16x32_bf16(al, bh, acc[nt], 0, 0, 0);
      acc[nt] = __builtin_amdgcn_mfma_f32_16x16x32_bf16(ah, bl, acc[nt], 0, 0, 0);
    }
  }

  // epilogue: relu(+b1), split hi/lo, packed u32 store (normal caching)
#pragma unroll
  for (int nt = 0; nt < 16; ++nt) {
    int col = nt * 16 + l15;
    float bb = b1s[col];
#pragma unroll
    for (int r = 0; r < 4; ++r) {
      int row = b0 + w * 16 + lg4 * 4 + r;
      float v = acc[nt][r] + bb;
      v = v > 0.f ? v : 0.f;
      unsigned short hi = f2bf(v);
      unsigned short lo = f2bf(v - bf2f(hi));
      H[(size_t)row * 256 + col] = (unsigned int)hi | ((unsigned int)lo << 16);
    }
  }
}

// ---------------- kB: GEMM2 + squash + u_hat + streaming-Gram routing -------
// (byte-identical to R6) 16 samples/WG, wave = agent. H loads and out stores
// are non-temporal so L2 keeps Wbh/W2 resident. W single-bf16.
__global__ __launch_bounds__(256, 3) void kB(const unsigned int* __restrict__ H,
                                             const float* __restrict__ b2,
                                             const unsigned short* __restrict__ W2h,
                                             const unsigned short* __restrict__ W2l,
                                             const unsigned short* __restrict__ Wbh,
                                             float* __restrict__ out) {
  // union: u_scr [0,4352) f32 (phases 1-2) / uc [0,13056) f32 = [64 rows][204]
  __shared__ float smem[13056];
  const int tid = threadIdx.x;
  const int a   = tid >> 6;   // wave = agent
  const int l   = tid & 63;
  const int l15 = l & 15;
  const int lg4 = l >> 4;
  const int k8  = lg4 * 8;
  const int b0  = blockIdx.x * 16;

  // ---- phase 1: GEMM2 (split-bf16) + b2 + squash -> u (f32 in u_scr)
  bf16x8 hh[2], hl[2];
#pragma unroll
  for (int kc = 0; kc < 2; ++kc) {
    const u32x4* hp = (const u32x4*)(H + (size_t)(b0 + l15) * 256 + a * 64 + kc * 32 + k8);
    u32x4 q0 = __builtin_nontemporal_load(hp);
    u32x4 q1 = __builtin_nontemporal_load(hp + 1);
    unsigned int pw[8] = {q0[0], q0[1], q0[2], q0[3], q1[0], q1[1], q1[2], q1[3]};
    BF8 vh, vl;
#pragma unroll
    for (int j = 0; j < 8; ++j) {
      vh.u[j] = (unsigned short)(pw[j] & 0xFFFFu);
      vl.u[j] = (unsigned short)(pw[j] >> 16);
    }
    hh[kc] = vh.b;
    hl[kc] = vl.b;
  }
  const f32x4 fz = {0.f, 0.f, 0.f, 0.f};
  f32x4 a2[4];
#pragma unroll
  for (int ot = 0; ot < 4; ++ot) a2[ot] = fz;
#pragma unroll
  for (int ot = 0; ot < 4; ++ot)
#pragma unroll
    for (int kc = 0; kc < 2; ++kc) {
      bf16x8 bh = *(const bf16x8*)(W2h + ((a * 64 + ot * 16 + l15) * 64 + kc * 32 + k8));
      bf16x8 bl = *(const bf16x8*)(W2l + ((a * 64 + ot * 16 + l15) * 64 + kc * 32 + k8));
      a2[ot] = __builtin_amdgcn_mfma_f32_16x16x32_bf16(hh[kc], bh, a2[ot], 0, 0, 0);
      a2[ot] = __builtin_amdgcn_mfma_f32_16x16x32_bf16(hl[kc], bh, a2[ot], 0, 0, 0);
      a2[ot] = __builtin_amdgcn_mfma_f32_16x16x32_bf16(hh[kc], bl, a2[ot], 0, 0, 0);
    }
  float b2v[4];
#pragma unroll
  for (int ot = 0; ot < 4; ++ot) b2v[ot] = b2[a * 64 + ot * 16 + l15];
#pragma unroll
  for (int r = 0; r < 4; ++r) {
    float up[4];
    float sq = 0.f;
#pragma unroll
    for (int ot = 0; ot < 4; ++ot) {
      float v = a2[ot][r] + b2v[ot];
      up[ot] = v;
      sq += v * v;
    }
    sq += __shfl_xor(sq, 1, 64);
    sq += __shfl_xor(sq, 2, 64);
    sq += __shfl_xor(sq, 4, 64);
    sq += __shfl_xor(sq, 8, 64);
    float scale = sq / ((1.f + sq) * sqrtf(sq + 1e-8f));
#pragma unroll
    for (int ot = 0; ot < 4; ++ot)
      smem[a * 1088 + (lg4 * 4 + r) * 68 + ot * 16 + l15] = scale * up[ot];
  }
  __syncthreads();

  // ---- phase 2: u A-frags (transpose read, split hi/lo)
  bf16x8 uah[2], ual[2];
#pragma unroll
  for (int kc = 0; kc < 2; ++kc) {
    float4 f0 = *(const float4*)&smem[a * 1088 + l15 * 68 + kc * 32 + k8];
    float4 f1 = *(const float4*)&smem[a * 1088 + l15 * 68 + kc * 32 + k8 + 4];
    float vv[8] = {f0.x, f0.y, f0.z, f0.w, f1.x, f1.y, f1.z, f1.w};
    BF8 vh, vl;
#pragma unroll
    for (int j = 0; j < 8; ++j) {
      unsigned short hi = f2bf(vv[j]);
      vh.u[j] = hi;
      vl.u[j] = f2bf(vv[j] - bf2f(hi));
    }
    uah[kc] = vh.b;
    ual[kc] = vl.b;
  }
  __syncthreads();  // u_scr dead; uc overlays it

  // ---- phase 3: u_hat MFMA (u hi/lo x W bf16, 2 terms), f32 accum
  f32x4 au[20];
#pragma unroll
  for (int nt = 0; nt < 20; ++nt) au[nt] = fz;
#pragma unroll
  for (int nt = 0; nt < 20; ++nt)
#pragma unroll
    for (int kc = 0; kc < 2; ++kc) {
      bf16x8 bh = *(const bf16x8*)(Wbh + ((size_t)(a * 320 + nt * 16 + l15) * 64 + kc * 32 + k8));
      au[nt] = __builtin_amdgcn_mfma_f32_16x16x32_bf16(uah[kc], bh, au[nt], 0, 0, 0);
      au[nt] = __builtin_amdgcn_mfma_f32_16x16x32_bf16(ual[kc], bh, au[nt], 0, 0, 0);
    }

  // ---- phase 4: streaming Gram accumulation (half 1 first, half 0 last so
  //      uc ends holding half 0 for the v pass)
  const int sid   = tid >> 4;
  const int jraw  = tid & 15;
  const bool jact = (jraw < 10);
  const int jj    = jact ? jraw : 9;
  const int rbase = sid * 204 + jj * 20;  // + ag*16*204

  float Gp[10];
#pragma unroll
  for (int p = 0; p < 10; ++p) Gp[p] = 0.f;

#pragma unroll
  for (int hh2 = 0; hh2 < 2; ++hh2) {
    const int half = 1 - hh2;
    if (hh2 > 0) __syncthreads();  // prev half's reads done before overwrite
#pragma unroll
    for (int q = 0; q < 10; ++q)
#pragma unroll
      for (int r = 0; r < 4; ++r)
        smem[(a * 16 + lg4 * 4 + r) * 204 + q * 20 + l15] = au[q * 2 + half][r];
    __syncthreads();
#pragma unroll
    for (int qq = 0; qq < 4; ++qq) {
      f32x4 f0 = *(const f32x4*)&smem[rbase + 0 * 3264 + qq * 4];
      f32x4 f1 = *(const f32x4*)&smem[rbase + 1 * 3264 + qq * 4];
      f32x4 f2 = *(const f32x4*)&smem[rbase + 2 * 3264 + qq * 4];
      f32x4 f3 = *(const f32x4*)&smem[rbase + 3 * 3264 + qq * 4];
#pragma unroll
      for (int e = 0; e < 4; ++e) {
        float v0 = f0[e], v1 = f1[e], v2 = f2[e], v3 = f3[e];
        Gp[0] += v0 * v0; Gp[1] += v0 * v1; Gp[2] += v0 * v2; Gp[3] += v0 * v3;
        Gp[4] += v1 * v1; Gp[5] += v1 * v2; Gp[6] += v1 * v3;
        Gp[7] += v2 * v2; Gp[8] += v2 * v3;
        Gp[9] += v3 * v3;
      }
    }
  }

  // ---- phase 5: 3 routing iterations on G (register-local)
  float cf0 = 0.f, cf1 = 0.f, cf2 = 0.f, cf3 = 0.f;
  {
    float lg0 = 0.f, lg1 = 0.f, lg2 = 0.f, lg3 = 0.f;
#pragma unroll
    for (int it = 0; it < 3; ++it) {
      float e0 = jact ? __expf(lg0) : 0.f;
      float e1 = jact ? __expf(lg1) : 0.f;
      float e2 = jact ? __expf(lg2) : 0.f;
      float e3 = jact ? __expf(lg3) : 0.f;
      float S0 = e0, S1 = e1, S2 = e2, S3 = e3;
#pragma unroll
      for (int m = 1; m <= 8; m <<= 1) {
        S0 += __shfl_xor(S0, m, 16);
        S1 += __shfl_xor(S1, m, 16);
        S2 += __shfl_xor(S2, m, 16);
        S3 += __shfl_xor(S3, m, 16);
      }
      float c0 = e0 / S0, c1 = e1 / S1, c2 = e2 / S2, c3 = e3 / S3;
      float t0 = c0 * Gp[0] + c1 * Gp[1] + c2 * Gp[2] + c3 * Gp[3];
      float t1 = c0 * Gp[1] + c1 * Gp[4] + c2 * Gp[5] + c3 * Gp[6];
      float t2 = c0 * Gp[2] + c1 * Gp[5] + c2 * Gp[7] + c3 * Gp[8];
      float t3 = c0 * Gp[3] + c1 * Gp[6] + c2 * Gp[8] + c3 * Gp[9];
      float sq = c0 * t0 + c1 * t1 + c2 * t2 + c3 * t3;
      float scale = sq / ((1.f + sq) * sqrtf(sq + 1e-8f));
      if (it < 2) {
        lg0 += scale * t0;
        lg1 += scale * t1;
        lg2 += scale * t2;
        lg3 += scale * t3;
      } else {
        cf0 = scale * c0;
        cf1 = scale * c1;
        cf2 = scale * c2;
        cf3 = scale * c3;
      }
    }
  }

  // ---- phase 6: v pass, streaming. uc holds half 0 (reads-after-reads ok).
  float* po = out + (size_t)(b0 + sid) * 320 + jraw * 32;
  if (jact) {
#pragma unroll
    for (int qq = 0; qq < 4; ++qq) {
      f32x4 f0 = *(const f32x4*)&smem[rbase + 0 * 3264 + qq * 4];
      f32x4 f1 = *(const f32x4*)&smem[rbase + 1 * 3264 + qq * 4];
      f32x4 f2 = *(const f32x4*)&smem[rbase + 2 * 3264 + qq * 4];
      f32x4 f3 = *(const f32x4*)&smem[rbase + 3 * 3264 + qq * 4];
      f32x4 v4;
#pragma unroll
      for (int e = 0; e < 4; ++e)
        v4[e] = cf0 * f0[e] + cf1 * f1[e] + cf2 * f2[e] + cf3 * f3[e];
      __builtin_nontemporal_store(v4, (f32x4*)(po + qq * 4));
    }
  }
  __syncthreads();  // v reads of half 0 done before overwrite
#pragma unroll
  for (int q = 0; q < 10; ++q)
#pragma unroll
    for (int r = 0; r < 4; ++r)
      smem[(a * 16 + lg4 * 4 + r) * 204 + q * 20 + l15] = au[q * 2 + 1][r];
  __syncthreads();
  if (jact) {
#pragma unroll
    for (int qq = 0; qq < 4; ++qq) {
      f32x4 f0 = *(const f32x4*)&smem[rbase + 0 * 3264 + qq * 4];
      f32x4 f1 = *(const f32x4*)&smem[rbase + 1 * 3264 + qq * 4];
      f32x4 f2 = *(const f32x4*)&smem[rbase + 2 * 3264 + qq * 4];
      f32x4 f3 = *(const f32x4*)&smem[rbase + 3 * 3264 + qq * 4];
      f32x4 v4;
#pragma unroll
      for (int e = 0; e < 4; ++e)
        v4[e] = cf0 * f0[e] + cf1 * f1[e] + cf2 * f2[e] + cf3 * f3[e];
      __builtin_nontemporal_store(v4, (f32x4*)(po + 16 + qq * 4));
    }
  }
}

extern "C" void kernel_launch(void* const* d_in, const int* in_sizes, int n_in,
                              void* d_out, int out_size, void* d_ws, size_t ws_size,
                              hipStream_t stream) {
  const float* x  = (const float*)d_in[0];
  const float* W1 = (const float*)d_in[1];
  const float* b1 = (const float*)d_in[2];
  const float* W2 = (const float*)d_in[3];
  const float* b2 = (const float*)d_in[4];
  const float* W  = (const float*)d_in[5];

  unsigned short* wsb = (unsigned short*)d_ws;
  unsigned short* W1h = wsb;                 // 204800
  unsigned short* W1l = wsb + 204800;        // 204800
  unsigned short* W2h = wsb + 409600;        // 16384
  unsigned short* W2l = wsb + 425984;        // 16384
  unsigned short* Wbh = wsb + 442368;        // 81920
  unsigned int*   H   = (unsigned int*)(wsb + 606208);  // 32768*256 u32
  float* out = (float*)d_out;

  kprep<<<800, 256, 0, stream>>>(W1, W2, W, W1h, W1l, W2h, W2l, Wbh);
  kA<<<512, 256, 0, stream>>>(x, b1, W1h, W1l, H);
  kB<<<2048, 256, 0, stream>>>(H, b2, W2h, W2l, Wbh, out);
}

// Round 8
// 168.252 us; speedup vs baseline: 1.3501x; 1.3501x over previous
//
#include <hip/hip_runtime.h>

typedef __bf16 bf16_t;
typedef bf16_t bf16x8 __attribute__((ext_vector_type(8)));
typedef unsigned short u16x8 __attribute__((ext_vector_type(8)));
typedef float f32x4 __attribute__((ext_vector_type(4)));
typedef unsigned int u32x4 __attribute__((ext_vector_type(4)));

union BF8 { u16x8 u; bf16x8 b; };

__device__ __forceinline__ unsigned short f2bf(float f) {
  unsigned int u = __float_as_uint(f);
  unsigned int r = (u + 0x7FFFu + ((u >> 16) & 1u)) >> 16;
  return (unsigned short)r;
}
__device__ __forceinline__ float bf2f(unsigned short s) {
  return __uint_as_float(((unsigned int)s) << 16);
}

// ---------------- prep: weights -> MFMA-frag-ready bf16 layouts --------------
// Wfh/Wfl: [25 ks][16 nt][64 lane][8] -- lane l holds W1[col=nt*16+(l&15)]
//          [k=ks*32+(l>>4)*8+e], zero-padded past k=784. Coalesced per wave.
// W2h/W2l: [4][64][64]  W2t[a][o][k] = W2[a][k][o]  (unchanged)
// Wfb:     [4 a][20 nt][2 kc][64 lane][8] -- lane l holds W[a][nt*16+(l&15)]
//          [kc*32+(l>>4)*8+e], single bf16.
__global__ __launch_bounds__(256) void kprep(const float* __restrict__ W1,
                                             const float* __restrict__ W2,
                                             const float* __restrict__ W,
                                             unsigned short* __restrict__ Wfh,
                                             unsigned short* __restrict__ Wfl,
                                             unsigned short* __restrict__ W2h,
                                             unsigned short* __restrict__ W2l,
                                             unsigned short* __restrict__ Wfb) {
  int idx = blockIdx.x * 256 + threadIdx.x;
  if (idx < 204800) {
    int e = idx & 7, lane = (idx >> 3) & 63, nt = (idx >> 9) & 15, ks = idx >> 13;
    int k = ks * 32 + (lane >> 4) * 8 + e;
    int col = nt * 16 + (lane & 15);
    int a = col >> 6, o = col & 63;
    float v = (k < 784) ? W1[(a * 784 + k) * 64 + o] : 0.f;
    unsigned short hi = f2bf(v);
    Wfh[idx] = hi;
    Wfl[idx] = f2bf(v - bf2f(hi));
  }
  if (idx < 16384) {
    int a = idx >> 12, o = (idx >> 6) & 63, k = idx & 63;
    float v = W2[(a * 64 + k) * 64 + o];
    unsigned short hi = f2bf(v);
    W2h[idx] = hi;
    W2l[idx] = f2bf(v - bf2f(hi));
  }
  if (idx < 81920) {
    int e = idx & 7;
    int t = idx >> 3;
    int lane = t & 63; t >>= 6;
    int kc = t & 1;   t >>= 1;
    int nt = t % 20;
    int a  = t / 20;
    int row = nt * 16 + (lane & 15);
    int kk  = kc * 32 + (lane >> 4) * 8 + e;
    Wfb[idx] = f2bf(W[(a * 320 + row) * 64 + kk]);
  }
}

// ---------------- kA: h = relu(x@W1 + b1), split-bf16, -> packed u32 ---------
// BM=64, 4 waves, wave = agent (4 nt cols) x 4 M-tiles. W1 B-frags read
// directly from global in frag-ready coalesced layout (L2-resident); only x
// is LDS-staged (hi/lo). 48 MFMA per 8 global-B + 8 LDS-A loads per k-step.
__global__ __launch_bounds__(256, 3) void kA(const float* __restrict__ x,
                                             const float* __restrict__ b1,
                                             const unsigned short* __restrict__ Wfh,
                                             const unsigned short* __restrict__ Wfl,
                                             unsigned int* __restrict__ H) {
  __shared__ unsigned short xsh[64 * 40];
  __shared__ unsigned short xsl[64 * 40];
  __shared__ float b1s[256];
  const int tid = threadIdx.x;
  const int w   = tid >> 6;
  const int l   = tid & 63;
  const int l15 = l & 15;
  const int lg4 = l >> 4;
  const int k8  = lg4 * 8;
  const int b0  = blockIdx.x * 64;

  b1s[tid] = b1[tid];

  const f32x4 fz = {0.f, 0.f, 0.f, 0.f};
  f32x4 acc[4][4];
#pragma unroll
  for (int mt = 0; mt < 4; ++mt)
#pragma unroll
    for (int n = 0; n < 4; ++n) acc[mt][n] = fz;

  const int srow = tid >> 2;        // x staging row 0..63
  const int skq  = (tid & 3) * 8;   // k-offset 0,8,16,24

  for (int ks = 0; ks < 25; ++ks) {
    const int k0 = ks * 32;
    __syncthreads();
    {  // stage x rows -> hi/lo bf16 LDS (zero-pad K 784->800)
      unsigned int ph[4], pl[4];
      if (k0 + skq < 784) {
        const float4* px = (const float4*)(x + (size_t)(b0 + srow) * 784 + k0 + skq);
        float4 v0 = px[0], v1 = px[1];
        float vv[8] = {v0.x, v0.y, v0.z, v0.w, v1.x, v1.y, v1.z, v1.w};
#pragma unroll
        for (int j = 0; j < 4; ++j) {
          unsigned short h0 = f2bf(vv[2 * j]), h1 = f2bf(vv[2 * j + 1]);
          unsigned short s0 = f2bf(vv[2 * j] - bf2f(h0));
          unsigned short s1 = f2bf(vv[2 * j + 1] - bf2f(h1));
          ph[j] = (unsigned int)h0 | ((unsigned int)h1 << 16);
          pl[j] = (unsigned int)s0 | ((unsigned int)s1 << 16);
        }
      } else {
#pragma unroll
        for (int j = 0; j < 4; ++j) { ph[j] = 0u; pl[j] = 0u; }
      }
      uint4 a0 = {ph[0], ph[1], ph[2], ph[3]};
      uint4 c0 = {pl[0], pl[1], pl[2], pl[3]};
      *(uint4*)&xsh[srow * 40 + skq] = a0;
      *(uint4*)&xsl[srow * 40 + skq] = c0;
    }
    __syncthreads();
    bf16x8 ah[4], al[4];
#pragma unroll
    for (int mt = 0; mt < 4; ++mt) {
      ah[mt] = *(const bf16x8*)&xsh[(mt * 16 + l15) * 40 + k8];
      al[mt] = *(const bf16x8*)&xsl[(mt * 16 + l15) * 40 + k8];
    }
#pragma unroll
    for (int n = 0; n < 4; ++n) {
      const int nt = w * 4 + n;
      bf16x8 bh = *(const bf16x8*)(Wfh + ((size_t)(ks * 16 + nt) * 64 + l) * 8);
      bf16x8 bl = *(const bf16x8*)(Wfl + ((size_t)(ks * 16 + nt) * 64 + l) * 8);
#pragma unroll
      for (int mt = 0; mt < 4; ++mt) {
        acc[mt][n] = __builtin_amdgcn_mfma_f32_16x16x32_bf16(ah[mt], bh, acc[mt][n], 0, 0, 0);
        acc[mt][n] = __builtin_amdgcn_mfma_f32_16x16x32_bf16(al[mt], bh, acc[mt][n], 0, 0, 0);
        acc[mt][n] = __builtin_amdgcn_mfma_f32_16x16x32_bf16(ah[mt], bl, acc[mt][n], 0, 0, 0);
      }
    }
  }

  // epilogue: relu(+b1), split hi/lo, packed u32 store
#pragma unroll
  for (int mt = 0; mt < 4; ++mt)
#pragma unroll
    for (int n = 0; n < 4; ++n) {
      int col = (w * 4 + n) * 16 + l15;
      float bb = b1s[col];
#pragma unroll
      for (int r = 0; r < 4; ++r) {
        int row = b0 + mt * 16 + lg4 * 4 + r;
        float v = acc[mt][n][r] + bb;
        v = v > 0.f ? v : 0.f;
        unsigned short hi = f2bf(v);
        unsigned short lo = f2bf(v - bf2f(hi));
        H[(size_t)row * 256 + col] = (unsigned int)hi | ((unsigned int)lo << 16);
      }
    }
}

// ---------------- kB: GEMM2 + squash + u_hat + streaming-Gram routing -------
// Same structure as R6/R7 (proven); only change: Wfb frag-ready coalesced
// B-frag loads in phase 3.
__global__ __launch_bounds__(256, 3) void kB(const unsigned int* __restrict__ H,
                                             const float* __restrict__ b2,
                                             const unsigned short* __restrict__ W2h,
                                             const unsigned short* __restrict__ W2l,
                                             const unsigned short* __restrict__ Wfb,
                                             float* __restrict__ out) {
  // union: u_scr [0,4352) f32 (phases 1-2) / uc [0,13056) f32 = [64 rows][204]
  __shared__ float smem[13056];
  const int tid = threadIdx.x;
  const int a   = tid >> 6;   // wave = agent
  const int l   = tid & 63;
  const int l15 = l & 15;
  const int lg4 = l >> 4;
  const int k8  = lg4 * 8;
  const int b0  = blockIdx.x * 16;

  // ---- phase 1: GEMM2 (split-bf16) + b2 + squash -> u (f32 in u_scr)
  bf16x8 hh[2], hl[2];
#pragma unroll
  for (int kc = 0; kc < 2; ++kc) {
    const u32x4* hp = (const u32x4*)(H + (size_t)(b0 + l15) * 256 + a * 64 + kc * 32 + k8);
    u32x4 q0 = __builtin_nontemporal_load(hp);
    u32x4 q1 = __builtin_nontemporal_load(hp + 1);
    unsigned int pw[8] = {q0[0], q0[1], q0[2], q0[3], q1[0], q1[1], q1[2], q1[3]};
    BF8 vh, vl;
#pragma unroll
    for (int j = 0; j < 8; ++j) {
      vh.u[j] = (unsigned short)(pw[j] & 0xFFFFu);
      vl.u[j] = (unsigned short)(pw[j] >> 16);
    }
    hh[kc] = vh.b;
    hl[kc] = vl.b;
  }
  const f32x4 fz = {0.f, 0.f, 0.f, 0.f};
  f32x4 a2[4];
#pragma unroll
  for (int ot = 0; ot < 4; ++ot) a2[ot] = fz;
#pragma unroll
  for (int ot = 0; ot < 4; ++ot)
#pragma unroll
    for (int kc = 0; kc < 2; ++kc) {
      bf16x8 bh = *(const bf16x8*)(W2h + ((a * 64 + ot * 16 + l15) * 64 + kc * 32 + k8));
      bf16x8 bl = *(const bf16x8*)(W2l + ((a * 64 + ot * 16 + l15) * 64 + kc * 32 + k8));
      a2[ot] = __builtin_amdgcn_mfma_f32_16x16x32_bf16(hh[kc], bh, a2[ot], 0, 0, 0);
      a2[ot] = __builtin_amdgcn_mfma_f32_16x16x32_bf16(hl[kc], bh, a2[ot], 0, 0, 0);
      a2[ot] = __builtin_amdgcn_mfma_f32_16x16x32_bf16(hh[kc], bl, a2[ot], 0, 0, 0);
    }
  float b2v[4];
#pragma unroll
  for (int ot = 0; ot < 4; ++ot) b2v[ot] = b2[a * 64 + ot * 16 + l15];
#pragma unroll
  for (int r = 0; r < 4; ++r) {
    float up[4];
    float sq = 0.f;
#pragma unroll
    for (int ot = 0; ot < 4; ++ot) {
      float v = a2[ot][r] + b2v[ot];
      up[ot] = v;
      sq += v * v;
    }
    sq += __shfl_xor(sq, 1, 64);
    sq += __shfl_xor(sq, 2, 64);
    sq += __shfl_xor(sq, 4, 64);
    sq += __shfl_xor(sq, 8, 64);
    float scale = sq / ((1.f + sq) * sqrtf(sq + 1e-8f));
#pragma unroll
    for (int ot = 0; ot < 4; ++ot)
      smem[a * 1088 + (lg4 * 4 + r) * 68 + ot * 16 + l15] = scale * up[ot];
  }
  __syncthreads();

  // ---- phase 2: u A-frags (transpose read, split hi/lo)
  bf16x8 uah[2], ual[2];
#pragma unroll
  for (int kc = 0; kc < 2; ++kc) {
    float4 f0 = *(const float4*)&smem[a * 1088 + l15 * 68 + kc * 32 + k8];
    float4 f1 = *(const float4*)&smem[a * 1088 + l15 * 68 + kc * 32 + k8 + 4];
    float vv[8] = {f0.x, f0.y, f0.z, f0.w, f1.x, f1.y, f1.z, f1.w};
    BF8 vh, vl;
#pragma unroll
    for (int j = 0; j < 8; ++j) {
      unsigned short hi = f2bf(vv[j]);
      vh.u[j] = hi;
      vl.u[j] = f2bf(vv[j] - bf2f(hi));
    }
    uah[kc] = vh.b;
    ual[kc] = vl.b;
  }
  __syncthreads();  // u_scr dead; uc overlays it

  // ---- phase 3: u_hat MFMA (u hi/lo x W bf16, 2 terms), coalesced frags
  f32x4 au[20];
#pragma unroll
  for (int nt = 0; nt < 20; ++nt) au[nt] = fz;
#pragma unroll
  for (int nt = 0; nt < 20; ++nt)
#pragma unroll
    for (int kc = 0; kc < 2; ++kc) {
      bf16x8 bh = *(const bf16x8*)(Wfb + ((size_t)((a * 20 + nt) * 2 + kc) * 64 + l) * 8);
      au[nt] = __builtin_amdgcn_mfma_f32_16x16x32_bf16(uah[kc], bh, au[nt], 0, 0, 0);
      au[nt] = __builtin_amdgcn_mfma_f32_16x16x32_bf16(ual[kc], bh, au[nt], 0, 0, 0);
    }

  // ---- phase 4: streaming Gram accumulation (half 1 first, half 0 last so
  //      uc ends holding half 0 for the v pass)
  const int sid   = tid >> 4;
  const int jraw  = tid & 15;
  const bool jact = (jraw < 10);
  const int jj    = jact ? jraw : 9;
  const int rbase = sid * 204 + jj * 20;  // + ag*16*204

  float Gp[10];
#pragma unroll
  for (int p = 0; p < 10; ++p) Gp[p] = 0.f;

#pragma unroll
  for (int hh2 = 0; hh2 < 2; ++hh2) {
    const int half = 1 - hh2;
    if (hh2 > 0) __syncthreads();  // prev half's reads done before overwrite
#pragma unroll
    for (int q = 0; q < 10; ++q)
#pragma unroll
      for (int r = 0; r < 4; ++r)
        smem[(a * 16 + lg4 * 4 + r) * 204 + q * 20 + l15] = au[q * 2 + half][r];
    __syncthreads();
#pragma unroll
    for (int qq = 0; qq < 4; ++qq) {
      f32x4 f0 = *(const f32x4*)&smem[rbase + 0 * 3264 + qq * 4];
      f32x4 f1 = *(const f32x4*)&smem[rbase + 1 * 3264 + qq * 4];
      f32x4 f2 = *(const f32x4*)&smem[rbase + 2 * 3264 + qq * 4];
      f32x4 f3 = *(const f32x4*)&smem[rbase + 3 * 3264 + qq * 4];
#pragma unroll
      for (int e = 0; e < 4; ++e) {
        float v0 = f0[e], v1 = f1[e], v2 = f2[e], v3 = f3[e];
        Gp[0] += v0 * v0; Gp[1] += v0 * v1; Gp[2] += v0 * v2; Gp[3] += v0 * v3;
        Gp[4] += v1 * v1; Gp[5] += v1 * v2; Gp[6] += v1 * v3;
        Gp[7] += v2 * v2; Gp[8] += v2 * v3;
        Gp[9] += v3 * v3;
      }
    }
  }

  // ---- phase 5: 3 routing iterations on G (register-local)
  float cf0 = 0.f, cf1 = 0.f, cf2 = 0.f, cf3 = 0.f;
  {
    float lg0 = 0.f, lg1 = 0.f, lg2 = 0.f, lg3 = 0.f;
#pragma unroll
    for (int it = 0; it < 3; ++it) {
      float e0 = jact ? __expf(lg0) : 0.f;
      float e1 = jact ? __expf(lg1) : 0.f;
      float e2 = jact ? __expf(lg2) : 0.f;
      float e3 = jact ? __expf(lg3) : 0.f;
      float S0 = e0, S1 = e1, S2 = e2, S3 = e3;
#pragma unroll
      for (int m = 1; m <= 8; m <<= 1) {
        S0 += __shfl_xor(S0, m, 16);
        S1 += __shfl_xor(S1, m, 16);
        S2 += __shfl_xor(S2, m, 16);
        S3 += __shfl_xor(S3, m, 16);
      }
      float c0 = e0 / S0, c1 = e1 / S1, c2 = e2 / S2, c3 = e3 / S3;
      float t0 = c0 * Gp[0] + c1 * Gp[1] + c2 * Gp[2] + c3 * Gp[3];
      float t1 = c0 * Gp[1] + c1 * Gp[4] + c2 * Gp[5] + c3 * Gp[6];
      float t2 = c0 * Gp[2] + c1 * Gp[5] + c2 * Gp[7] + c3 * Gp[8];
      float t3 = c0 * Gp[3] + c1 * Gp[6] + c2 * Gp[8] + c3 * Gp[9];
      float sq = c0 * t0 + c1 * t1 + c2 * t2 + c3 * t3;
      float scale = sq / ((1.f + sq) * sqrtf(sq + 1e-8f));
      if (it < 2) {
        lg0 += scale * t0;
        lg1 += scale * t1;
        lg2 += scale * t2;
        lg3 += scale * t3;
      } else {
        cf0 = scale * c0;
        cf1 = scale * c1;
        cf2 = scale * c2;
        cf3 = scale * c3;
      }
    }
  }

  // ---- phase 6: v pass, streaming. uc holds half 0 (reads-after-reads ok).
  float* po = out + (size_t)(b0 + sid) * 320 + jraw * 32;
  if (jact) {
#pragma unroll
    for (int qq = 0; qq < 4; ++qq) {
      f32x4 f0 = *(const f32x4*)&smem[rbase + 0 * 3264 + qq * 4];
      f32x4 f1 = *(const f32x4*)&smem[rbase + 1 * 3264 + qq * 4];
      f32x4 f2 = *(const f32x4*)&smem[rbase + 2 * 3264 + qq * 4];
      f32x4 f3 = *(const f32x4*)&smem[rbase + 3 * 3264 + qq * 4];
      f32x4 v4;
#pragma unroll
      for (int e = 0; e < 4; ++e)
        v4[e] = cf0 * f0[e] + cf1 * f1[e] + cf2 * f2[e] + cf3 * f3[e];
      __builtin_nontemporal_store(v4, (f32x4*)(po + qq * 4));
    }
  }
  __syncthreads();  // v reads of half 0 done before overwrite
#pragma unroll
  for (int q = 0; q < 10; ++q)
#pragma unroll
    for (int r = 0; r < 4; ++r)
      smem[(a * 16 + lg4 * 4 + r) * 204 + q * 20 + l15] = au[q * 2 + 1][r];
  __syncthreads();
  if (jact) {
#pragma unroll
    for (int qq = 0; qq < 4; ++qq) {
      f32x4 f0 = *(const f32x4*)&smem[rbase + 0 * 3264 + qq * 4];
      f32x4 f1 = *(const f32x4*)&smem[rbase + 1 * 3264 + qq * 4];
      f32x4 f2 = *(const f32x4*)&smem[rbase + 2 * 3264 + qq * 4];
      f32x4 f3 = *(const f32x4*)&smem[rbase + 3 * 3264 + qq * 4];
      f32x4 v4;
#pragma unroll
      for (int e = 0; e < 4; ++e)
        v4[e] = cf0 * f0[e] + cf1 * f1[e] + cf2 * f2[e] + cf3 * f3[e];
      __builtin_nontemporal_store(v4, (f32x4*)(po + 16 + qq * 4));
    }
  }
}

extern "C" void kernel_launch(void* const* d_in, const int* in_sizes, int n_in,
                              void* d_out, int out_size, void* d_ws, size_t ws_size,
                              hipStream_t stream) {
  const float* x  = (const float*)d_in[0];
  const float* W1 = (const float*)d_in[1];
  const float* b1 = (const float*)d_in[2];
  const float* W2 = (const float*)d_in[3];
  const float* b2 = (const float*)d_in[4];
  const float* W  = (const float*)d_in[5];

  unsigned short* wsb = (unsigned short*)d_ws;
  unsigned short* Wfh = wsb;                 // 204800 (frag layout)
  unsigned short* Wfl = wsb + 204800;        // 204800
  unsigned short* W2h = wsb + 409600;        // 16384
  unsigned short* W2l = wsb + 425984;        // 16384
  unsigned short* Wfb = wsb + 442368;        // 81920 (frag layout)
  unsigned int*   H   = (unsigned int*)(wsb + 606208);  // 32768*256 u32
  float* out = (float*)d_out;

  kprep<<<800, 256, 0, stream>>>(W1, W2, W, Wfh, Wfl, W2h, W2l, Wfb);
  kA<<<512, 256, 0, stream>>>(x, b1, Wfh, Wfl, H);
  kB<<<2048, 256, 0, stream>>>(H, b2, W2h, W2l, Wfb, out);
}

// Round 9
// 102.591 us; speedup vs baseline: 2.2142x; 1.6400x over previous
//
#include <hip/hip_runtime.h>

typedef __bf16 bf16_t;
typedef bf16_t bf16x8 __attribute__((ext_vector_type(8)));
typedef unsigned short u16x8 __attribute__((ext_vector_type(8)));
typedef float f32x4 __attribute__((ext_vector_type(4)));
typedef unsigned int u32x4 __attribute__((ext_vector_type(4)));

union BF8 { u16x8 u; bf16x8 b; };

__device__ __forceinline__ unsigned short f2bf(float f) {
  unsigned int u = __float_as_uint(f);
  unsigned int r = (u + 0x7FFFu + ((u >> 16) & 1u)) >> 16;
  return (unsigned short)r;
}
__device__ __forceinline__ float bf2f(unsigned short s) {
  return __uint_as_float(((unsigned int)s) << 16);
}

// ---------------- prep: weights -> MFMA-frag-ready bf16 layouts --------------
// Wfh/Wfl: [25 ks][16 nt][64 lane][8] -- lane l holds W1[col=nt*16+(l&15)]
//          [k=ks*32+(l>>4)*8+e], zero-padded past k=784. Coalesced per wave.
// W2h/W2l: [4][64][64]  W2t[a][o][k] = W2[a][k][o]
// Wfb:     [4 a][20 nt][2 kc][64 lane][8] -- single bf16, frag-ready.
__global__ __launch_bounds__(256) void kprep(const float* __restrict__ W1,
                                             const float* __restrict__ W2,
                                             const float* __restrict__ W,
                                             unsigned short* __restrict__ Wfh,
                                             unsigned short* __restrict__ Wfl,
                                             unsigned short* __restrict__ W2h,
                                             unsigned short* __restrict__ W2l,
                                             unsigned short* __restrict__ Wfb) {
  int idx = blockIdx.x * 256 + threadIdx.x;
  if (idx < 204800) {
    int e = idx & 7, lane = (idx >> 3) & 63, nt = (idx >> 9) & 15, ks = idx >> 13;
    int k = ks * 32 + (lane >> 4) * 8 + e;
    int col = nt * 16 + (lane & 15);
    int a = col >> 6, o = col & 63;
    float v = (k < 784) ? W1[(a * 784 + k) * 64 + o] : 0.f;
    unsigned short hi = f2bf(v);
    Wfh[idx] = hi;
    Wfl[idx] = f2bf(v - bf2f(hi));
  }
  if (idx < 16384) {
    int a = idx >> 12, o = (idx >> 6) & 63, k = idx & 63;
    float v = W2[(a * 64 + k) * 64 + o];
    unsigned short hi = f2bf(v);
    W2h[idx] = hi;
    W2l[idx] = f2bf(v - bf2f(hi));
  }
  if (idx < 81920) {
    int e = idx & 7;
    int t = idx >> 3;
    int lane = t & 63; t >>= 6;
    int kc = t & 1;   t >>= 1;
    int nt = t % 20;
    int a  = t / 20;
    int row = nt * 16 + (lane & 15);
    int kk  = kc * 32 + (lane >> 4) * 8 + e;
    Wfb[idx] = f2bf(W[(a * 320 + row) * 64 + kk]);
  }
}

// ---------------- kA: h = relu(x@W1 + b1), split-bf16, -> packed u32 ---------
// 512 threads (8 waves), BM=64, wave = 2 col-tiles x 4 M-tiles. x double-
// buffered in LDS (1 barrier/iter, next-x issued before the barrier); W1
// B-frags direct from global in frag-ready layout (L2-resident). 2 blocks/CU
// -> 4 waves/SIMD.
__global__ __launch_bounds__(512, 4) void kA(const float* __restrict__ x,
                                             const float* __restrict__ b1,
                                             const unsigned short* __restrict__ Wfh,
                                             const unsigned short* __restrict__ Wfl,
                                             unsigned int* __restrict__ H) {
  __shared__ unsigned short xsh[2][64 * 40];
  __shared__ unsigned short xsl[2][64 * 40];
  __shared__ float b1s[256];
  const int tid = threadIdx.x;
  const int w   = tid >> 6;        // wave 0..7
  const int l   = tid & 63;
  const int l15 = l & 15;
  const int lg4 = l >> 4;
  const int k8  = lg4 * 8;
  const int b0  = blockIdx.x * 64;

  if (tid < 256) b1s[tid] = b1[tid];

  const f32x4 fz = {0.f, 0.f, 0.f, 0.f};
  f32x4 acc[4][2];
#pragma unroll
  for (int mt = 0; mt < 4; ++mt)
#pragma unroll
    for (int n = 0; n < 2; ++n) acc[mt][n] = fz;

  // staging decomposition: thread = (row 0..63, k-quad 0..7), one f32x4 each
  const int srow = tid >> 3;
  const int skq  = (tid & 7) * 4;  // k offset in floats (0..28)
  const float* xrow = x + (size_t)(b0 + srow) * 784;

  // prologue: load+pack ks=0 into buf 0
  {
    f32x4 xv = fz;
    if (skq < 784) xv = *(const f32x4*)(xrow + skq);
    unsigned int ph[2], pl[2];
#pragma unroll
    for (int j = 0; j < 2; ++j) {
      unsigned short h0 = f2bf(xv[2 * j]), h1 = f2bf(xv[2 * j + 1]);
      unsigned short s0 = f2bf(xv[2 * j] - bf2f(h0));
      unsigned short s1 = f2bf(xv[2 * j + 1] - bf2f(h1));
      ph[j] = (unsigned int)h0 | ((unsigned int)h1 << 16);
      pl[j] = (unsigned int)s0 | ((unsigned int)s1 << 16);
    }
    *(uint2*)&xsh[0][srow * 40 + skq] = *(uint2*)ph;
    *(uint2*)&xsl[0][srow * 40 + skq] = *(uint2*)pl;
  }

  for (int ks = 0; ks < 25; ++ks) {
    const int cur = ks & 1;
    // issue next-step x load before the barrier (HBM latency hides under MFMA)
    f32x4 xn = fz;
    if (ks < 24) {
      int kf = (ks + 1) * 32 + skq;
      if (kf < 784) xn = *(const f32x4*)(xrow + kf);
    }
    __syncthreads();  // buf[cur] writes (prev iter) visible; buf[cur^1] reads done

    // W B-frags for this step (direct, coalesced, L2-resident)
    const int nt0 = w * 2;
    bf16x8 bh0 = *(const bf16x8*)(Wfh + ((size_t)(ks * 16 + nt0) * 64 + l) * 8);
    bf16x8 bl0 = *(const bf16x8*)(Wfl + ((size_t)(ks * 16 + nt0) * 64 + l) * 8);
    bf16x8 bh1 = *(const bf16x8*)(Wfh + ((size_t)(ks * 16 + nt0 + 1) * 64 + l) * 8);
    bf16x8 bl1 = *(const bf16x8*)(Wfl + ((size_t)(ks * 16 + nt0 + 1) * 64 + l) * 8);

    // A-frags from LDS
    bf16x8 ah[4], al[4];
#pragma unroll
    for (int mt = 0; mt < 4; ++mt) {
      ah[mt] = *(const bf16x8*)&xsh[cur][(mt * 16 + l15) * 40 + k8];
      al[mt] = *(const bf16x8*)&xsl[cur][(mt * 16 + l15) * 40 + k8];
    }

#pragma unroll
    for (int mt = 0; mt < 4; ++mt) {
      acc[mt][0] = __builtin_amdgcn_mfma_f32_16x16x32_bf16(ah[mt], bh0, acc[mt][0], 0, 0, 0);
      acc[mt][0] = __builtin_amdgcn_mfma_f32_16x16x32_bf16(al[mt], bh0, acc[mt][0], 0, 0, 0);
      acc[mt][0] = __builtin_amdgcn_mfma_f32_16x16x32_bf16(ah[mt], bl0, acc[mt][0], 0, 0, 0);
      acc[mt][1] = __builtin_amdgcn_mfma_f32_16x16x32_bf16(ah[mt], bh1, acc[mt][1], 0, 0, 0);
      acc[mt][1] = __builtin_amdgcn_mfma_f32_16x16x32_bf16(al[mt], bh1, acc[mt][1], 0, 0, 0);
      acc[mt][1] = __builtin_amdgcn_mfma_f32_16x16x32_bf16(ah[mt], bl1, acc[mt][1], 0, 0, 0);
    }

    // pack + stage next x into the other buffer
    if (ks < 24) {
      unsigned int ph[2], pl[2];
#pragma unroll
      for (int j = 0; j < 2; ++j) {
        unsigned short h0 = f2bf(xn[2 * j]), h1 = f2bf(xn[2 * j + 1]);
        unsigned short s0 = f2bf(xn[2 * j] - bf2f(h0));
        unsigned short s1 = f2bf(xn[2 * j + 1] - bf2f(h1));
        ph[j] = (unsigned int)h0 | ((unsigned int)h1 << 16);
        pl[j] = (unsigned int)s0 | ((unsigned int)s1 << 16);
      }
      *(uint2*)&xsh[cur ^ 1][srow * 40 + skq] = *(uint2*)ph;
      *(uint2*)&xsl[cur ^ 1][srow * 40 + skq] = *(uint2*)pl;
    }
  }

  // epilogue: relu(+b1), split hi/lo, packed u32 store
#pragma unroll
  for (int mt = 0; mt < 4; ++mt)
#pragma unroll
    for (int n = 0; n < 2; ++n) {
      int col = (w * 2 + n) * 16 + l15;
      float bb = b1s[col];
#pragma unroll
      for (int r = 0; r < 4; ++r) {
        int row = b0 + mt * 16 + lg4 * 4 + r;
        float v = acc[mt][n][r] + bb;
        v = v > 0.f ? v : 0.f;
        unsigned short hi = f2bf(v);
        unsigned short lo = f2bf(v - bf2f(hi));
        H[(size_t)row * 256 + col] = (unsigned int)hi | ((unsigned int)lo << 16);
      }
    }
}

// ---------------- kB: GEMM2 + squash + u_hat + streaming-Gram routing -------
// Identical to R8 except out stores are NORMAL (nt caused 3.4x HBM write
// amplification: 16B stores at 128B lane-stride can't merge without L2).
__global__ __launch_bounds__(256, 3) void kB(const unsigned int* __restrict__ H,
                                             const float* __restrict__ b2,
                                             const unsigned short* __restrict__ W2h,
                                             const unsigned short* __restrict__ W2l,
                                             const unsigned short* __restrict__ Wfb,
                                             float* __restrict__ out) {
  // union: u_scr [0,4352) f32 (phases 1-2) / uc [0,13056) f32 = [64 rows][204]
  __shared__ float smem[13056];
  const int tid = threadIdx.x;
  const int a   = tid >> 6;   // wave = agent
  const int l   = tid & 63;
  const int l15 = l & 15;
  const int lg4 = l >> 4;
  const int k8  = lg4 * 8;
  const int b0  = blockIdx.x * 16;

  // ---- phase 1: GEMM2 (split-bf16) + b2 + squash -> u (f32 in u_scr)
  bf16x8 hh[2], hl[2];
#pragma unroll
  for (int kc = 0; kc < 2; ++kc) {
    const u32x4* hp = (const u32x4*)(H + (size_t)(b0 + l15) * 256 + a * 64 + kc * 32 + k8);
    u32x4 q0 = __builtin_nontemporal_load(hp);
    u32x4 q1 = __builtin_nontemporal_load(hp + 1);
    unsigned int pw[8] = {q0[0], q0[1], q0[2], q0[3], q1[0], q1[1], q1[2], q1[3]};
    BF8 vh, vl;
#pragma unroll
    for (int j = 0; j < 8; ++j) {
      vh.u[j] = (unsigned short)(pw[j] & 0xFFFFu);
      vl.u[j] = (unsigned short)(pw[j] >> 16);
    }
    hh[kc] = vh.b;
    hl[kc] = vl.b;
  }
  const f32x4 fz = {0.f, 0.f, 0.f, 0.f};
  f32x4 a2[4];
#pragma unroll
  for (int ot = 0; ot < 4; ++ot) a2[ot] = fz;
#pragma unroll
  for (int ot = 0; ot < 4; ++ot)
#pragma unroll
    for (int kc = 0; kc < 2; ++kc) {
      bf16x8 bh = *(const bf16x8*)(W2h + ((a * 64 + ot * 16 + l15) * 64 + kc * 32 + k8));
      bf16x8 bl = *(const bf16x8*)(W2l + ((a * 64 + ot * 16 + l15) * 64 + kc * 32 + k8));
      a2[ot] = __builtin_amdgcn_mfma_f32_16x16x32_bf16(hh[kc], bh, a2[ot], 0, 0, 0);
      a2[ot] = __builtin_amdgcn_mfma_f32_16x16x32_bf16(hl[kc], bh, a2[ot], 0, 0, 0);
      a2[ot] = __builtin_amdgcn_mfma_f32_16x16x32_bf16(hh[kc], bl, a2[ot], 0, 0, 0);
    }
  float b2v[4];
#pragma unroll
  for (int ot = 0; ot < 4; ++ot) b2v[ot] = b2[a * 64 + ot * 16 + l15];
#pragma unroll
  for (int r = 0; r < 4; ++r) {
    float up[4];
    float sq = 0.f;
#pragma unroll
    for (int ot = 0; ot < 4; ++ot) {
      float v = a2[ot][r] + b2v[ot];
      up[ot] = v;
      sq += v * v;
    }
    sq += __shfl_xor(sq, 1, 64);
    sq += __shfl_xor(sq, 2, 64);
    sq += __shfl_xor(sq, 4, 64);
    sq += __shfl_xor(sq, 8, 64);
    float scale = sq / ((1.f + sq) * sqrtf(sq + 1e-8f));
#pragma unroll
    for (int ot = 0; ot < 4; ++ot)
      smem[a * 1088 + (lg4 * 4 + r) * 68 + ot * 16 + l15] = scale * up[ot];
  }
  __syncthreads();

  // ---- phase 2: u A-frags (transpose read, split hi/lo)
  bf16x8 uah[2], ual[2];
#pragma unroll
  for (int kc = 0; kc < 2; ++kc) {
    float4 f0 = *(const float4*)&smem[a * 1088 + l15 * 68 + kc * 32 + k8];
    float4 f1 = *(const float4*)&smem[a * 1088 + l15 * 68 + kc * 32 + k8 + 4];
    float vv[8] = {f0.x, f0.y, f0.z, f0.w, f1.x, f1.y, f1.z, f1.w};
    BF8 vh, vl;
#pragma unroll
    for (int j = 0; j < 8; ++j) {
      unsigned short hi = f2bf(vv[j]);
      vh.u[j] = hi;
      vl.u[j] = f2bf(vv[j] - bf2f(hi));
    }
    uah[kc] = vh.b;
    ual[kc] = vl.b;
  }
  __syncthreads();  // u_scr dead; uc overlays it

  // ---- phase 3: u_hat MFMA (u hi/lo x W bf16, 2 terms), coalesced frags
  f32x4 au[20];
#pragma unroll
  for (int nt = 0; nt < 20; ++nt) au[nt] = fz;
#pragma unroll
  for (int nt = 0; nt < 20; ++nt)
#pragma unroll
    for (int kc = 0; kc < 2; ++kc) {
      bf16x8 bh = *(const bf16x8*)(Wfb + ((size_t)((a * 20 + nt) * 2 + kc) * 64 + l) * 8);
      au[nt] = __builtin_amdgcn_mfma_f32_16x16x32_bf16(uah[kc], bh, au[nt], 0, 0, 0);
      au[nt] = __builtin_amdgcn_mfma_f32_16x16x32_bf16(ual[kc], bh, au[nt], 0, 0, 0);
    }

  // ---- phase 4: streaming Gram accumulation (half 1 first, half 0 last so
  //      uc ends holding half 0 for the v pass)
  const int sid   = tid >> 4;
  const int jraw  = tid & 15;
  const bool jact = (jraw < 10);
  const int jj    = jact ? jraw : 9;
  const int rbase = sid * 204 + jj * 20;  // + ag*16*204

  float Gp[10];
#pragma unroll
  for (int p = 0; p < 10; ++p) Gp[p] = 0.f;

#pragma unroll
  for (int hh2 = 0; hh2 < 2; ++hh2) {
    const int half = 1 - hh2;
    if (hh2 > 0) __syncthreads();  // prev half's reads done before overwrite
#pragma unroll
    for (int q = 0; q < 10; ++q)
#pragma unroll
      for (int r = 0; r < 4; ++r)
        smem[(a * 16 + lg4 * 4 + r) * 204 + q * 20 + l15] = au[q * 2 + half][r];
    __syncthreads();
#pragma unroll
    for (int qq = 0; qq < 4; ++qq) {
      f32x4 f0 = *(const f32x4*)&smem[rbase + 0 * 3264 + qq * 4];
      f32x4 f1 = *(const f32x4*)&smem[rbase + 1 * 3264 + qq * 4];
      f32x4 f2 = *(const f32x4*)&smem[rbase + 2 * 3264 + qq * 4];
      f32x4 f3 = *(const f32x4*)&smem[rbase + 3 * 3264 + qq * 4];
#pragma unroll
      for (int e = 0; e < 4; ++e) {
        float v0 = f0[e], v1 = f1[e], v2 = f2[e], v3 = f3[e];
        Gp[0] += v0 * v0; Gp[1] += v0 * v1; Gp[2] += v0 * v2; Gp[3] += v0 * v3;
        Gp[4] += v1 * v1; Gp[5] += v1 * v2; Gp[6] += v1 * v3;
        Gp[7] += v2 * v2; Gp[8] += v2 * v3;
        Gp[9] += v3 * v3;
      }
    }
  }

  // ---- phase 5: 3 routing iterations on G (register-local)
  float cf0 = 0.f, cf1 = 0.f, cf2 = 0.f, cf3 = 0.f;
  {
    float lg0 = 0.f, lg1 = 0.f, lg2 = 0.f, lg3 = 0.f;
#pragma unroll
    for (int it = 0; it < 3; ++it) {
      float e0 = jact ? __expf(lg0) : 0.f;
      float e1 = jact ? __expf(lg1) : 0.f;
      float e2 = jact ? __expf(lg2) : 0.f;
      float e3 = jact ? __expf(lg3) : 0.f;
      float S0 = e0, S1 = e1, S2 = e2, S3 = e3;
#pragma unroll
      for (int m = 1; m <= 8; m <<= 1) {
        S0 += __shfl_xor(S0, m, 16);
        S1 += __shfl_xor(S1, m, 16);
        S2 += __shfl_xor(S2, m, 16);
        S3 += __shfl_xor(S3, m, 16);
      }
      float c0 = e0 / S0, c1 = e1 / S1, c2 = e2 / S2, c3 = e3 / S3;
      float t0 = c0 * Gp[0] + c1 * Gp[1] + c2 * Gp[2] + c3 * Gp[3];
      float t1 = c0 * Gp[1] + c1 * Gp[4] + c2 * Gp[5] + c3 * Gp[6];
      float t2 = c0 * Gp[2] + c1 * Gp[5] + c2 * Gp[7] + c3 * Gp[8];
      float t3 = c0 * Gp[3] + c1 * Gp[6] + c2 * Gp[8] + c3 * Gp[9];
      float sq = c0 * t0 + c1 * t1 + c2 * t2 + c3 * t3;
      float scale = sq / ((1.f + sq) * sqrtf(sq + 1e-8f));
      if (it < 2) {
        lg0 += scale * t0;
        lg1 += scale * t1;
        lg2 += scale * t2;
        lg3 += scale * t3;
      } else {
        cf0 = scale * c0;
        cf1 = scale * c1;
        cf2 = scale * c2;
        cf3 = scale * c3;
      }
    }
  }

  // ---- phase 6: v pass, streaming. uc holds half 0 (reads-after-reads ok).
  float* po = out + (size_t)(b0 + sid) * 320 + jraw * 32;
  if (jact) {
#pragma unroll
    for (int qq = 0; qq < 4; ++qq) {
      f32x4 f0 = *(const f32x4*)&smem[rbase + 0 * 3264 + qq * 4];
      f32x4 f1 = *(const f32x4*)&smem[rbase + 1 * 3264 + qq * 4];
      f32x4 f2 = *(const f32x4*)&smem[rbase + 2 * 3264 + qq * 4];
      f32x4 f3 = *(const f32x4*)&smem[rbase + 3 * 3264 + qq * 4];
      f32x4 v4;
#pragma unroll
      for (int e = 0; e < 4; ++e)
        v4[e] = cf0 * f0[e] + cf1 * f1[e] + cf2 * f2[e] + cf3 * f3[e];
      *(f32x4*)(po + qq * 4) = v4;
    }
  }
  __syncthreads();  // v reads of half 0 done before overwrite
#pragma unroll
  for (int q = 0; q < 10; ++q)
#pragma unroll
    for (int r = 0; r < 4; ++r)
      smem[(a * 16 + lg4 * 4 + r) * 204 + q * 20 + l15] = au[q * 2 + 1][r];
  __syncthreads();
  if (jact) {
#pragma unroll
    for (int qq = 0; qq < 4; ++qq) {
      f32x4 f0 = *(const f32x4*)&smem[rbase + 0 * 3264 + qq * 4];
      f32x4 f1 = *(const f32x4*)&smem[rbase + 1 * 3264 + qq * 4];
      f32x4 f2 = *(const f32x4*)&smem[rbase + 2 * 3264 + qq * 4];
      f32x4 f3 = *(const f32x4*)&smem[rbase + 3 * 3264 + qq * 4];
      f32x4 v4;
#pragma unroll
      for (int e = 0; e < 4; ++e)
        v4[e] = cf0 * f0[e] + cf1 * f1[e] + cf2 * f2[e] + cf3 * f3[e];
      *(f32x4*)(po + 16 + qq * 4) = v4;
    }
  }
}

extern "C" void kernel_launch(void* const* d_in, const int* in_sizes, int n_in,
                              void* d_out, int out_size, void* d_ws, size_t ws_size,
                              hipStream_t stream) {
  const float* x  = (const float*)d_in[0];
  const float* W1 = (const float*)d_in[1];
  const float* b1 = (const float*)d_in[2];
  const float* W2 = (const float*)d_in[3];
  const float* b2 = (const float*)d_in[4];
  const float* W  = (const float*)d_in[5];

  unsigned short* wsb = (unsigned short*)d_ws;
  unsigned short* Wfh = wsb;                 // 204800 (frag layout)
  unsigned short* Wfl = wsb + 204800;        // 204800
  unsigned short* W2h = wsb + 409600;        // 16384
  unsigned short* W2l = wsb + 425984;        // 16384
  unsigned short* Wfb = wsb + 442368;        // 81920 (frag layout)
  unsigned int*   H   = (unsigned int*)(wsb + 606208);  // 32768*256 u32
  float* out = (float*)d_out;

  kprep<<<800, 256, 0, stream>>>(W1, W2, W, Wfh, Wfl, W2h, W2l, Wfb);
  kA<<<512, 512, 0, stream>>>(x, b1, Wfh, Wfl, H);
  kB<<<2048, 256, 0, stream>>>(H, b2, W2h, W2l, Wfb, out);
}